// Round 3
// baseline (10731.213 us; speedup 1.0000x reference)
//
#include <hip/hip_runtime.h>

#define LAYERS 4
#define BATCH  64
#define SEQ    256
#define HID    1024

typedef _Float16 half8 __attribute__((ext_vector_type(8)));
typedef _Float16 half4 __attribute__((ext_vector_type(4)));
typedef float    f32x4 __attribute__((ext_vector_type(4)));

__device__ __forceinline__ float sig_(float x) { return 1.0f / (1.0f + __expf(-x)); }
__device__ __forceinline__ float th_(float x)  { return 2.0f / (1.0f + __expf(-2.0f * x)) - 1.0f; }

__device__ __forceinline__ half8 ld8h(const _Float16* p) { return *(const half8*)p; }
__device__ __forceinline__ half8 cvt8(const float* p) {
    f32x4 a = *(const f32x4*)p;
    f32x4 b = *(const f32x4*)(p + 4);
    half8 r;
    r[0] = (_Float16)a[0]; r[1] = (_Float16)a[1]; r[2] = (_Float16)a[2]; r[3] = (_Float16)a[3];
    r[4] = (_Float16)b[0]; r[5] = (_Float16)b[1]; r[6] = (_Float16)b[2]; r[7] = (_Float16)b[3];
    return r;
}

// fp32 -> f16 elementwise (n multiple of 4)
__global__ void k_cvt(const float* __restrict__ src, _Float16* __restrict__ dst, long n) {
    long i = ((long)blockIdx.x * blockDim.x + threadIdx.x) * 4;
    if (i >= n) return;
    f32x4 s = *(const f32x4*)(src + i);
    half4 d;
    d[0] = (_Float16)s[0]; d[1] = (_Float16)s[1]; d[2] = (_Float16)s[2]; d[3] = (_Float16)s[3];
    *(half4*)(dst + i) = d;
}

__global__ void k_bias(const float* __restrict__ bih, const float* __restrict__ bhh,
                       float* __restrict__ bias) {
    int i = blockIdx.x * blockDim.x + threadIdx.x;
    if (i < LAYERS * 4 * HID) bias[i] = bih[i] + bhh[i];
}

// Diagonal-schedule fused LSTM step. One launch per global step s.
// Layer l = blockIdx.x>>6 processes t = s - l. Block owns 16 hidden cols (all
// 4 gates); 4 waves = 4 batch M-tiles of 16.
// MFMA 16x16x32 f16: A[m=lane&15][k=quad*8+j]; B[k=quad*8+j][n=lane&15];
// D: col=lane&15, row=quad*4+reg.
// CVT=true: weights/x pre-converted to f16 in ws. CVT=false: read fp32, convert in-register.
template <bool CVT>
__global__ __launch_bounds__(256) void k_step(
        int s,
        const float*    __restrict__ x32,   // [B, T, H] fp32
        const _Float16* __restrict__ x16,   // [B, T, H] f16 (CVT path)
        const float*    __restrict__ wih32, // [L, 4H, H] fp32
        const float*    __restrict__ whh32,
        const _Float16* __restrict__ wih16, // f16 copies (CVT path)
        const _Float16* __restrict__ whh16,
        const float*    __restrict__ bias,  // [L, 4H]
        _Float16*       __restrict__ hbuf,  // [L][2 parity][B][H] f16
        float*          __restrict__ cst,   // [L][B][H] fp32
        float*          __restrict__ out)   // [B, H] fp32
{
    const int layer = blockIdx.x >> 6;
    const int t = s - layer;
    if (t < 0 || t >= SEQ) return;

    const int j0   = (blockIdx.x & 63) << 4;
    const int lane = threadIdx.x & 63;
    const int wave = threadIdx.x >> 6;
    const int nl   = lane & 15;
    const int quad = lane >> 4;
    const int m0   = wave << 4;
    const int q8   = quad * 8;

    const size_t BH = (size_t)BATCH * HID;
    const size_t wbase = (size_t)layer * 4 * HID * HID + (size_t)(j0 + nl) * HID + q8;

    // A operands
    const _Float16* ah16 = hbuf + ((size_t)layer * 2 + ((t + 1) & 1)) * BH
                                + (size_t)(m0 + nl) * HID + q8;      // own h_{t-1}
    const float*    ax32 = nullptr;
    const _Float16* ax16 = nullptr;
    size_t in_row;
    if (layer == 0) {
        in_row = (size_t)(m0 + nl) * SEQ * HID + (size_t)t * HID + q8; // x[b][t][.]
        if (CVT) ax16 = x16 + in_row; else ax32 = x32 + in_row;
    } else {
        ax16 = hbuf + ((size_t)(layer - 1) * 2 + (t & 1)) * BH
                    + (size_t)(m0 + nl) * HID + q8;
    }

    f32x4 acc0 = {0,0,0,0}, acc1 = {0,0,0,0}, acc2 = {0,0,0,0}, acc3 = {0,0,0,0};

    #pragma unroll 2
    for (int k = 0; k < HID; k += 32) {
        half8 ax = (layer == 0 && !CVT) ? cvt8(ax32 + k) : ld8h(ax16 + k);
        half8 ah = ld8h(ah16 + k);

        half8 w;
        if (CVT) w = ld8h(wih16 + wbase + 0 * HID * HID + k); else w = cvt8(wih32 + wbase + 0 * HID * HID + k);
        acc0 = __builtin_amdgcn_mfma_f32_16x16x32_f16(ax, w, acc0, 0,0,0);
        if (CVT) w = ld8h(whh16 + wbase + 0 * HID * HID + k); else w = cvt8(whh32 + wbase + 0 * HID * HID + k);
        acc0 = __builtin_amdgcn_mfma_f32_16x16x32_f16(ah, w, acc0, 0,0,0);

        if (CVT) w = ld8h(wih16 + wbase + 1 * HID * HID + k); else w = cvt8(wih32 + wbase + 1 * HID * HID + k);
        acc1 = __builtin_amdgcn_mfma_f32_16x16x32_f16(ax, w, acc1, 0,0,0);
        if (CVT) w = ld8h(whh16 + wbase + 1 * HID * HID + k); else w = cvt8(whh32 + wbase + 1 * HID * HID + k);
        acc1 = __builtin_amdgcn_mfma_f32_16x16x32_f16(ah, w, acc1, 0,0,0);

        if (CVT) w = ld8h(wih16 + wbase + 2 * HID * HID + k); else w = cvt8(wih32 + wbase + 2 * HID * HID + k);
        acc2 = __builtin_amdgcn_mfma_f32_16x16x32_f16(ax, w, acc2, 0,0,0);
        if (CVT) w = ld8h(whh16 + wbase + 2 * HID * HID + k); else w = cvt8(whh32 + wbase + 2 * HID * HID + k);
        acc2 = __builtin_amdgcn_mfma_f32_16x16x32_f16(ah, w, acc2, 0,0,0);

        if (CVT) w = ld8h(wih16 + wbase + 3 * HID * HID + k); else w = cvt8(wih32 + wbase + 3 * HID * HID + k);
        acc3 = __builtin_amdgcn_mfma_f32_16x16x32_f16(ax, w, acc3, 0,0,0);
        if (CVT) w = ld8h(whh16 + wbase + 3 * HID * HID + k); else w = cvt8(whh32 + wbase + 3 * HID * HID + k);
        acc3 = __builtin_amdgcn_mfma_f32_16x16x32_f16(ah, w, acc3, 0,0,0);
    }

    // epilogue
    const int j = j0 + nl;
    const float bi_ = bias[layer * 4 * HID + j];
    const float bf_ = bias[layer * 4 * HID + HID + j];
    const float bg_ = bias[layer * 4 * HID + 2 * HID + j];
    const float bo_ = bias[layer * 4 * HID + 3 * HID + j];
    _Float16* o_h = hbuf + ((size_t)layer * 2 + (t & 1)) * BH;
    float*    c   = cst + (size_t)layer * BH;
    const bool last = (layer == LAYERS - 1) && (t == SEQ - 1);

    #pragma unroll
    for (int r = 0; r < 4; ++r) {
        int m = m0 + quad * 4 + r;
        size_t idx = (size_t)m * HID + j;
        float gi = acc0[r] + bi_;
        float gf = acc1[r] + bf_;
        float gg = acc2[r] + bg_;
        float go = acc3[r] + bo_;
        float cn = sig_(gf) * c[idx] + sig_(gi) * th_(gg);
        c[idx] = cn;
        float hn = sig_(go) * th_(cn);
        o_h[idx] = (_Float16)hn;
        if (last) out[idx] = hn;
    }
}

extern "C" void kernel_launch(void* const* d_in, const int* in_sizes, int n_in,
                              void* d_out, int out_size, void* d_ws, size_t ws_size,
                              hipStream_t stream) {
    const float* x     = (const float*)d_in[0];
    const float* wih32 = (const float*)d_in[1];
    const float* whh32 = (const float*)d_in[2];
    const float* bih   = (const float*)d_in[3];
    const float* bhh   = (const float*)d_in[4];
    (void)in_sizes; (void)n_in; (void)out_size;

    const size_t BH     = (size_t)BATCH * HID;
    const size_t W_ELS  = (size_t)LAYERS * 4 * HID * HID;  // 16,777,216 per matrix
    const size_t X_ELS  = (size_t)BATCH * SEQ * HID;       // 16,777,216

    char* ws = (char*)d_ws;
    size_t off = 0;
    _Float16* hbuf = (_Float16*)(ws + off); off += (size_t)LAYERS * 2 * BH * 2; // 1 MB
    float*    cst  = (float*)   (ws + off); off += (size_t)LAYERS * BH * 4;     // 1 MB
    size_t zero_bytes = off;
    float*    bias = (float*)   (ws + off); off += (size_t)LAYERS * 4 * HID * 4;
    _Float16* wih16 = (_Float16*)(ws + off); off += W_ELS * 2;                  // 33.5 MB
    _Float16* whh16 = (_Float16*)(ws + off); off += W_ELS * 2;                  // 33.5 MB
    _Float16* x16   = (_Float16*)(ws + off); off += X_ELS * 2;                  // 33.5 MB
    const bool cvt = (ws_size >= off);  // full-conversion path fits?

    hipMemsetAsync(ws, 0, zero_bytes, stream);
    k_bias<<<(LAYERS * 4 * HID + 255) / 256, 256, 0, stream>>>(bih, bhh, bias);

    if (cvt) {
        k_cvt<<<(int)((W_ELS / 4 + 255) / 256), 256, 0, stream>>>(wih32, wih16, (long)W_ELS);
        k_cvt<<<(int)((W_ELS / 4 + 255) / 256), 256, 0, stream>>>(whh32, whh16, (long)W_ELS);
        k_cvt<<<(int)((X_ELS / 4 + 255) / 256), 256, 0, stream>>>(x, x16, (long)X_ELS);
        for (int s = 0; s < SEQ + LAYERS - 1; ++s)
            k_step<true><<<LAYERS * 64, 256, 0, stream>>>(
                s, x, x16, wih32, whh32, wih16, whh16, bias, hbuf, cst, (float*)d_out);
    } else {
        for (int s = 0; s < SEQ + LAYERS - 1; ++s)
            k_step<false><<<LAYERS * 64, 256, 0, stream>>>(
                s, x, nullptr, wih32, whh32, nullptr, nullptr, bias, hbuf, cst, (float*)d_out);
    }
}

// Round 4
// 4489.777 us; speedup vs baseline: 2.3901x; 2.3901x over previous
//
#include <hip/hip_runtime.h>

#define LAYERS 4
#define BATCH  64
#define SEQ    256
#define HID    1024

typedef _Float16 half8 __attribute__((ext_vector_type(8)));
typedef _Float16 half4 __attribute__((ext_vector_type(4)));
typedef float    f32x4 __attribute__((ext_vector_type(4)));

__device__ __forceinline__ float sig_(float x) { return 1.0f / (1.0f + __expf(-x)); }
__device__ __forceinline__ float th_(float x)  { return 2.0f / (1.0f + __expf(-2.0f * x)) - 1.0f; }

__global__ void k_bias(const float* __restrict__ bih, const float* __restrict__ bhh,
                       float* __restrict__ bias) {
    int i = blockIdx.x * blockDim.x + threadIdx.x;
    if (i < LAYERS * 4 * HID) bias[i] = bih[i] + bhh[i];
}

// Pack weights fp32 -> f16 in per-wave MFMA fragment order:
// chunk c = ((((l*2+mat)*4+g)*64+jblk)*32+i)*64+lane, 8 els each.
// lane=(quad,nl): src row = l*4H + g*H + jblk*16 + nl, col = i*32 + quad*8.
__global__ void k_packw(const float* __restrict__ wih32, const float* __restrict__ whh32,
                        _Float16* __restrict__ wpack) {
    unsigned c = blockIdx.x * blockDim.x + threadIdx.x;   // < 2^22
    int lane = c & 63, i = (c >> 6) & 31, jblk = (c >> 11) & 63;
    int g = (c >> 17) & 3, mat = (c >> 19) & 1, l = c >> 20;
    const float* src = (mat ? whh32 : wih32)
        + ((size_t)l * 4 * HID + (size_t)g * HID + jblk * 16 + (lane & 15)) * HID
        + i * 32 + (lane >> 4) * 8;
    f32x4 a = *(const f32x4*)src;
    f32x4 b = *(const f32x4*)(src + 4);
    half8 d;
    d[0]=(_Float16)a[0]; d[1]=(_Float16)a[1]; d[2]=(_Float16)a[2]; d[3]=(_Float16)a[3];
    d[4]=(_Float16)b[0]; d[5]=(_Float16)b[1]; d[6]=(_Float16)b[2]; d[7]=(_Float16)b[3];
    *(half8*)(wpack + (size_t)c * 8) = d;
}

// Pack x fp32 [B,T,H] -> f16 fragment order per t: chunk c = ((t*4+mt)*32+i)*64+lane.
__global__ void k_packx(const float* __restrict__ x32, _Float16* __restrict__ xpack) {
    unsigned c = blockIdx.x * blockDim.x + threadIdx.x;   // < 2^21
    int lane = c & 63, i = (c >> 6) & 31, mt = (c >> 11) & 3, t = c >> 13;
    int m = mt * 16 + (lane & 15);
    int k = i * 32 + (lane >> 4) * 8;
    const float* src = x32 + ((size_t)m * SEQ + t) * HID + k;
    f32x4 a = *(const f32x4*)src;
    f32x4 b = *(const f32x4*)(src + 4);
    half8 d;
    d[0]=(_Float16)a[0]; d[1]=(_Float16)a[1]; d[2]=(_Float16)a[2]; d[3]=(_Float16)a[3];
    d[4]=(_Float16)b[0]; d[5]=(_Float16)b[1]; d[6]=(_Float16)b[2]; d[7]=(_Float16)b[3];
    *(half8*)(xpack + (size_t)c * 8) = d;
}

// Diagonal-schedule LSTM step. 256 blocks (layer = bid>>6, 16 cols each),
// 512 threads = 8 waves: wave = (kh, g); kh=0: x-side (W_ih), kh=1: h-side (W_hh).
// Each W fragment read exactly ONCE per step (no cross-wave redundancy).
// All K-loop loads are contiguous 1 KB/wave (fragment-packed layouts).
// Epilogue: LDS gate-plane reduce (kh pairs) + fused bias/sigmoid/tanh/c-update,
// h written back directly in fragment-packed order.
__global__ __launch_bounds__(512) void k_step(
        int s,
        const _Float16* __restrict__ xpack,  // [T][mt][i][lane][8] f16
        const _Float16* __restrict__ wpack,  // packed weights
        const float*    __restrict__ bias,   // [L][4H]
        _Float16*       __restrict__ hbuf,   // [L][2 parity][BH] f16, packed order
        float*          __restrict__ cst,    // [L][B][H] fp32, row-major
        float*          __restrict__ out)    // [B, H] fp32
{
    const int layer = blockIdx.x >> 6;
    const int t = s - layer;
    if (t < 0 || t >= SEQ) return;

    __shared__ __align__(16) float gplane[8][64][20];   // 40 KB, +4 pad vs banks

    const int tid  = threadIdx.x;
    const int wave = tid >> 6;
    const int g    = wave & 3;
    const int kh   = wave >> 2;
    const int lane = tid & 63;
    const int nl   = lane & 15;
    const int quad = lane >> 4;
    const int jblk = blockIdx.x & 63;
    const int j0   = jblk << 4;
    const size_t BH = (size_t)BATCH * HID;

    // A operand base (fragment-packed)
    const _Float16* Abase;
    if (kh == 0) {
        Abase = (layer == 0) ? (xpack + (size_t)t * BH)
                             : (hbuf + ((size_t)(layer - 1) * 2 + (t & 1)) * BH);
    } else {
        Abase = hbuf + ((size_t)layer * 2 + ((t + 1) & 1)) * BH;
    }
    const _Float16* Ap = Abase + (size_t)lane * 8;
    const size_t wchunk0 = ((((size_t)layer * 2 + kh) * 4 + g) * 64 + jblk) * (32 * 64);
    const _Float16* Wp = wpack + (wchunk0 + lane) * 8;

    f32x4 acc[4];
    #pragma unroll
    for (int mt = 0; mt < 4; ++mt) acc[mt] = (f32x4){0,0,0,0};

    #pragma unroll 4
    for (int i = 0; i < 32; ++i) {
        half8 w = *(const half8*)(Wp + (size_t)i * 512);
        #pragma unroll
        for (int mt = 0; mt < 4; ++mt) {
            half8 a = *(const half8*)(Ap + (size_t)mt * 16384 + (size_t)i * 512);
            acc[mt] = __builtin_amdgcn_mfma_f32_16x16x32_f16(a, w, acc[mt], 0, 0, 0);
        }
    }

    // stash partial gates: D layout col=nl, row=quad*4+r (within 16-row M-tile)
    #pragma unroll
    for (int mt = 0; mt < 4; ++mt)
        #pragma unroll
        for (int r = 0; r < 4; ++r)
            gplane[wave][mt * 16 + quad * 4 + r][nl] = acc[mt][r];
    __syncthreads();

    if (tid < 256) {
        const int m  = tid >> 2;
        const int jg = tid & 3;
        const int jA = j0 + jg * 4;

        f32x4 vi = *(const f32x4*)&gplane[0][m][jg*4] + *(const f32x4*)&gplane[4][m][jg*4];
        f32x4 vf = *(const f32x4*)&gplane[1][m][jg*4] + *(const f32x4*)&gplane[5][m][jg*4];
        f32x4 vg = *(const f32x4*)&gplane[2][m][jg*4] + *(const f32x4*)&gplane[6][m][jg*4];
        f32x4 vo = *(const f32x4*)&gplane[3][m][jg*4] + *(const f32x4*)&gplane[7][m][jg*4];

        const float* bb = bias + (size_t)layer * 4 * HID;
        f32x4 bi = *(const f32x4*)(bb + 0 * HID + jA);
        f32x4 bf = *(const f32x4*)(bb + 1 * HID + jA);
        f32x4 bg = *(const f32x4*)(bb + 2 * HID + jA);
        f32x4 bo = *(const f32x4*)(bb + 3 * HID + jA);

        float* cp = cst + (size_t)layer * BH + (size_t)m * HID + jA;
        f32x4 c = *(const f32x4*)cp;
        f32x4 cn, hn;
        #pragma unroll
        for (int i = 0; i < 4; ++i) {
            float gi = vi[i] + bi[i];
            float gf = vf[i] + bf[i];
            float gg = vg[i] + bg[i];
            float go = vo[i] + bo[i];
            cn[i] = sig_(gf) * c[i] + sig_(gi) * th_(gg);
            hn[i] = sig_(go) * th_(cn[i]);
        }
        *(f32x4*)cp = cn;

        // write h in fragment-packed order
        _Float16* hp = hbuf + ((size_t)layer * 2 + (t & 1)) * BH;
        int i_  = jA >> 5;
        int qd  = (jA >> 3) & 3;
        int jj  = jA & 7;           // 0 or 4
        size_t hoff = (size_t)(m >> 4) * 16384 + (size_t)i_ * 512 + qd * 128 + (m & 15) * 8 + jj;
        half4 h4;
        h4[0]=(_Float16)hn[0]; h4[1]=(_Float16)hn[1]; h4[2]=(_Float16)hn[2]; h4[3]=(_Float16)hn[3];
        *(half4*)(hp + hoff) = h4;

        if (layer == LAYERS - 1 && t == SEQ - 1)
            *(f32x4*)(out + (size_t)m * HID + jA) = hn;
    }
}

extern "C" void kernel_launch(void* const* d_in, const int* in_sizes, int n_in,
                              void* d_out, int out_size, void* d_ws, size_t ws_size,
                              hipStream_t stream) {
    const float* x32   = (const float*)d_in[0];
    const float* wih32 = (const float*)d_in[1];
    const float* whh32 = (const float*)d_in[2];
    const float* bih   = (const float*)d_in[3];
    const float* bhh   = (const float*)d_in[4];
    (void)in_sizes; (void)n_in; (void)out_size; (void)ws_size;

    const size_t BH = (size_t)BATCH * HID;
    char* ws = (char*)d_ws;
    size_t off = 0;
    _Float16* hbuf  = (_Float16*)(ws + off); off += (size_t)LAYERS * 2 * BH * 2;      // 1 MB
    float*    cst   = (float*)   (ws + off); off += (size_t)LAYERS * BH * 4;          // 1 MB
    size_t zero_bytes = off;
    float*    bias  = (float*)   (ws + off); off += (size_t)LAYERS * 4 * HID * 4;     // 64 KB
    _Float16* wpack = (_Float16*)(ws + off); off += (size_t)2 * LAYERS * 4 * HID * HID * 2; // 67 MB
    _Float16* xpack = (_Float16*)(ws + off); off += (size_t)SEQ * BH * 2;             // 33.5 MB

    hipMemsetAsync(ws, 0, zero_bytes, stream);
    k_bias<<<(LAYERS * 4 * HID + 255) / 256, 256, 0, stream>>>(bih, bhh, bias);
    k_packw<<<(1u << 22) / 256, 256, 0, stream>>>(wih32, whh32, wpack);
    k_packx<<<(1u << 21) / 256, 256, 0, stream>>>(x32, xpack);

    for (int s = 0; s < SEQ + LAYERS - 1; ++s)
        k_step<<<LAYERS * 64, 512, 0, stream>>>(
            s, xpack, wpack, bias, hbuf, cst, (float*)d_out);
}

// Round 5
// 4436.686 us; speedup vs baseline: 2.4187x; 1.0120x over previous
//
#include <hip/hip_runtime.h>

#define LAYERS 4
#define BATCH  64
#define SEQ    256
#define HID    1024

typedef _Float16 half8 __attribute__((ext_vector_type(8)));
typedef _Float16 half4 __attribute__((ext_vector_type(4)));
typedef float    f32x4 __attribute__((ext_vector_type(4)));

__device__ __forceinline__ float sig_(float x) { return 1.0f / (1.0f + __expf(-x)); }
__device__ __forceinline__ float th_(float x)  { return 2.0f / (1.0f + __expf(-2.0f * x)) - 1.0f; }

__global__ void k_bias(const float* __restrict__ bih, const float* __restrict__ bhh,
                       float* __restrict__ bias) {
    int i = blockIdx.x * blockDim.x + threadIdx.x;
    if (i < LAYERS * 4 * HID) bias[i] = bih[i] + bhh[i];
}

// Pack weights fp32 -> f16, gate-major per-wave fragment order:
// c = (((((l*2+kh)*64+jblk)*4+q)*8+il)*4+g)*64+lane, 8 els per chunk.
// src row = l*4H + g*H + jblk*16 + (lane&15), col = (q*8+il)*32 + (lane>>4)*8.
__global__ void k_packw(const float* __restrict__ wih32, const float* __restrict__ whh32,
                        _Float16* __restrict__ wpack) {
    unsigned c = blockIdx.x * blockDim.x + threadIdx.x;   // < 2^22
    int lane = c & 63, g = (c >> 6) & 3, il = (c >> 8) & 7, q = (c >> 11) & 3;
    int jblk = (c >> 13) & 63, kh = (c >> 19) & 1, l = (int)(c >> 20);
    const float* src = (kh ? whh32 : wih32)
        + ((size_t)l * 4 * HID + (size_t)g * HID + jblk * 16 + (lane & 15)) * HID
        + (q * 8 + il) * 32 + (lane >> 4) * 8;
    f32x4 a = *(const f32x4*)src;
    f32x4 b = *(const f32x4*)(src + 4);
    half8 d;
    d[0]=(_Float16)a[0]; d[1]=(_Float16)a[1]; d[2]=(_Float16)a[2]; d[3]=(_Float16)a[3];
    d[4]=(_Float16)b[0]; d[5]=(_Float16)b[1]; d[6]=(_Float16)b[2]; d[7]=(_Float16)b[3];
    *(half8*)(wpack + (size_t)c * 8) = d;
}

// Pack x fp32 [B,T,H] -> f16 fragment order per t: c = ((t*4+mt)*32+i)*64+lane.
__global__ void k_packx(const float* __restrict__ x32, _Float16* __restrict__ xpack) {
    unsigned c = blockIdx.x * blockDim.x + threadIdx.x;   // < 2^21
    int lane = c & 63, i = (c >> 6) & 31, mt = (c >> 11) & 3, t = (int)(c >> 13);
    int m = mt * 16 + (lane & 15);
    int k = i * 32 + (lane >> 4) * 8;
    const float* src = x32 + ((size_t)m * SEQ + t) * HID + k;
    f32x4 a = *(const f32x4*)src;
    f32x4 b = *(const f32x4*)(src + 4);
    half8 d;
    d[0]=(_Float16)a[0]; d[1]=(_Float16)a[1]; d[2]=(_Float16)a[2]; d[3]=(_Float16)a[3];
    d[4]=(_Float16)b[0]; d[5]=(_Float16)b[1]; d[6]=(_Float16)b[2]; d[7]=(_Float16)b[3];
    *(half8*)(xpack + (size_t)c * 8) = d;
}

// Diagonal-schedule LSTM step, gate-major. 256 blocks (layer = bid>>6, 16 cols),
// 512 threads = 8 waves: wave = (kh, q); each wave computes ALL 4 gates over
// K-quarter q of side kh -> every A and W fragment read exactly once per block.
// 8-way partial-gate reduction via 32 KB LDS plane, two m-halves.
__global__ __launch_bounds__(512) void k_step(
        int s,
        const _Float16* __restrict__ xpack,  // [T][mt][i][lane][8] f16
        const _Float16* __restrict__ wpack,  // gate-major packed weights
        const float*    __restrict__ bias,   // [L][4H]
        _Float16*       __restrict__ hbuf,   // [L][2 parity][BH] f16, fragment order
        float*          __restrict__ cst,    // [L][B][H] fp32 row-major
        float*          __restrict__ out)    // [B, H] fp32
{
    const int layer = blockIdx.x >> 6;
    const int t = s - layer;
    if (t < 0 || t >= SEQ) return;

    __shared__ __align__(16) float gplane[4][4][32][16];   // [q][g][m_local][nl] 32 KB

    const int tid  = threadIdx.x;
    const int wave = tid >> 6;
    const int q    = wave & 3;
    const int kh   = wave >> 2;
    const int lane = tid & 63;
    const int nl   = lane & 15;
    const int quad = lane >> 4;
    const int jblk = blockIdx.x & 63;
    const int j0   = jblk << 4;
    const size_t BH = (size_t)BATCH * HID;

    // A operand base (fragment-packed), this wave's K-quarter
    const _Float16* Abase;
    if (kh == 0) {
        Abase = (layer == 0) ? (xpack + (size_t)t * BH)
                             : (hbuf + ((size_t)(layer - 1) * 2 + (t & 1)) * BH);
    } else {
        Abase = hbuf + ((size_t)layer * 2 + ((t + 1) & 1)) * BH;
    }
    const _Float16* Ap = Abase + (size_t)q * 4096 + (size_t)lane * 8;
    const _Float16* Wp = wpack
        + ((((size_t)layer * 2 + kh) * 64 + jblk) * 4 + q) * 16384
        + (size_t)lane * 8;

    f32x4 acc[4][4];   // [mt][g]
    #pragma unroll
    for (int mt = 0; mt < 4; ++mt)
        #pragma unroll
        for (int g = 0; g < 4; ++g) acc[mt][g] = (f32x4){0,0,0,0};

    #pragma unroll
    for (int il = 0; il < 8; ++il) {
        half8 w0 = *(const half8*)(Wp + il * 2048 + 0 * 512);
        half8 w1 = *(const half8*)(Wp + il * 2048 + 1 * 512);
        half8 w2 = *(const half8*)(Wp + il * 2048 + 2 * 512);
        half8 w3 = *(const half8*)(Wp + il * 2048 + 3 * 512);
        #pragma unroll
        for (int mt = 0; mt < 4; ++mt) {
            half8 a = *(const half8*)(Ap + (size_t)mt * 16384 + il * 512);
            acc[mt][0] = __builtin_amdgcn_mfma_f32_16x16x32_f16(a, w0, acc[mt][0], 0,0,0);
            acc[mt][1] = __builtin_amdgcn_mfma_f32_16x16x32_f16(a, w1, acc[mt][1], 0,0,0);
            acc[mt][2] = __builtin_amdgcn_mfma_f32_16x16x32_f16(a, w2, acc[mt][2], 0,0,0);
            acc[mt][3] = __builtin_amdgcn_mfma_f32_16x16x32_f16(a, w3, acc[mt][3], 0,0,0);
        }
    }

    // 8-way reduction + cell update, two m-halves (32 rows each)
    const float* bb = bias + (size_t)layer * 4 * HID;
    _Float16* hp = hbuf + ((size_t)layer * 2 + (t & 1)) * BH;
    const bool last = (layer == LAYERS - 1) && (t == SEQ - 1);

    #pragma unroll
    for (int half = 0; half < 2; ++half) {
        // phase A: kh=1 waves deposit partials
        if (kh == 1) {
            #pragma unroll
            for (int mtl = 0; mtl < 2; ++mtl)
                #pragma unroll
                for (int g = 0; g < 4; ++g)
                    #pragma unroll
                    for (int r = 0; r < 4; ++r)
                        gplane[q][g][mtl * 16 + quad * 4 + r][nl] = acc[half * 2 + mtl][g][r];
        }
        __syncthreads();
        // phase B: kh=0 waves add theirs
        if (kh == 0) {
            #pragma unroll
            for (int mtl = 0; mtl < 2; ++mtl)
                #pragma unroll
                for (int g = 0; g < 4; ++g)
                    #pragma unroll
                    for (int r = 0; r < 4; ++r)
                        gplane[q][g][mtl * 16 + quad * 4 + r][nl] += acc[half * 2 + mtl][g][r];
        }
        __syncthreads();
        // phase C: combine q-partials, LSTM cell, write h (fragment order)
        if (tid < 128) {
            const int ml = tid >> 2;          // 0..31
            const int jg = tid & 3;
            const int m  = half * 32 + ml;
            const int jA = j0 + jg * 4;

            f32x4 vi = *(const f32x4*)&gplane[0][0][ml][jg*4] + *(const f32x4*)&gplane[1][0][ml][jg*4]
                     + *(const f32x4*)&gplane[2][0][ml][jg*4] + *(const f32x4*)&gplane[3][0][ml][jg*4];
            f32x4 vf = *(const f32x4*)&gplane[0][1][ml][jg*4] + *(const f32x4*)&gplane[1][1][ml][jg*4]
                     + *(const f32x4*)&gplane[2][1][ml][jg*4] + *(const f32x4*)&gplane[3][1][ml][jg*4];
            f32x4 vg = *(const f32x4*)&gplane[0][2][ml][jg*4] + *(const f32x4*)&gplane[1][2][ml][jg*4]
                     + *(const f32x4*)&gplane[2][2][ml][jg*4] + *(const f32x4*)&gplane[3][2][ml][jg*4];
            f32x4 vo = *(const f32x4*)&gplane[0][3][ml][jg*4] + *(const f32x4*)&gplane[1][3][ml][jg*4]
                     + *(const f32x4*)&gplane[2][3][ml][jg*4] + *(const f32x4*)&gplane[3][3][ml][jg*4];

            f32x4 bi = *(const f32x4*)(bb + 0 * HID + jA);
            f32x4 bf = *(const f32x4*)(bb + 1 * HID + jA);
            f32x4 bg = *(const f32x4*)(bb + 2 * HID + jA);
            f32x4 bo = *(const f32x4*)(bb + 3 * HID + jA);

            float* cp = cst + (size_t)layer * BH + (size_t)m * HID + jA;
            f32x4 c = *(const f32x4*)cp;
            f32x4 cn, hn;
            #pragma unroll
            for (int i = 0; i < 4; ++i) {
                float gi = vi[i] + bi[i];
                float gf = vf[i] + bf[i];
                float gg = vg[i] + bg[i];
                float go = vo[i] + bo[i];
                cn[i] = sig_(gf) * c[i] + sig_(gi) * th_(gg);
                hn[i] = sig_(go) * th_(cn[i]);
            }
            *(f32x4*)cp = cn;

            // h in fragment-packed order: el (m, j) -> mt*16384 + i*512 + quad*128 + nl*8 + (j&7)
            int i_ = jA >> 5, qd = (jA >> 3) & 3, jj = jA & 7;
            size_t hoff = (size_t)(m >> 4) * 16384 + (size_t)i_ * 512 + qd * 128 + (m & 15) * 8 + jj;
            half4 h4;
            h4[0]=(_Float16)hn[0]; h4[1]=(_Float16)hn[1]; h4[2]=(_Float16)hn[2]; h4[3]=(_Float16)hn[3];
            *(half4*)(hp + hoff) = h4;

            if (last) *(f32x4*)(out + (size_t)m * HID + jA) = hn;
        }
        __syncthreads();
    }
}

extern "C" void kernel_launch(void* const* d_in, const int* in_sizes, int n_in,
                              void* d_out, int out_size, void* d_ws, size_t ws_size,
                              hipStream_t stream) {
    const float* x32   = (const float*)d_in[0];
    const float* wih32 = (const float*)d_in[1];
    const float* whh32 = (const float*)d_in[2];
    const float* bih   = (const float*)d_in[3];
    const float* bhh   = (const float*)d_in[4];
    (void)in_sizes; (void)n_in; (void)out_size; (void)ws_size;

    const size_t BH = (size_t)BATCH * HID;
    char* ws = (char*)d_ws;
    size_t off = 0;
    _Float16* hbuf  = (_Float16*)(ws + off); off += (size_t)LAYERS * 2 * BH * 2;      // 1 MB
    float*    cst   = (float*)   (ws + off); off += (size_t)LAYERS * BH * 4;          // 1 MB
    size_t zero_bytes = off;
    float*    bias  = (float*)   (ws + off); off += (size_t)LAYERS * 4 * HID * 4;     // 64 KB
    _Float16* wpack = (_Float16*)(ws + off); off += (size_t)2 * LAYERS * 4 * HID * HID * 2; // 67 MB
    _Float16* xpack = (_Float16*)(ws + off); off += (size_t)SEQ * BH * 2;             // 33.5 MB

    hipMemsetAsync(ws, 0, zero_bytes, stream);
    k_bias<<<(LAYERS * 4 * HID + 255) / 256, 256, 0, stream>>>(bih, bhh, bias);
    k_packw<<<(1u << 22) / 256, 256, 0, stream>>>(wih32, whh32, wpack);
    k_packx<<<(1u << 21) / 256, 256, 0, stream>>>(x32, xpack);

    for (int s = 0; s < SEQ + LAYERS - 1; ++s)
        k_step<<<LAYERS * 64, 512, 0, stream>>>(
            s, xpack, wpack, bias, hbuf, cst, (float*)d_out);
}